// Round 1
// baseline (191.745 us; speedup 1.0000x reference)
//
#include <hip/hip_runtime.h>

typedef unsigned short u16;
typedef __attribute__((ext_vector_type(4))) float f32x4;
typedef __attribute__((ext_vector_type(8))) short bf16x8;

#define MFMA16(a, b, c) __builtin_amdgcn_mfma_f32_16x16x32_bf16(a, b, c, 0, 0, 0)

// fp32 -> bf16 with round-to-nearest-even (finite inputs only)
__device__ __forceinline__ u16 f2bf(float f) {
    union { float f; unsigned u; } v;
    v.f = f;
    unsigned r = v.u + 0x7FFFu + ((v.u >> 16) & 1u);
    return (u16)(r >> 16);
}

__device__ __forceinline__ int4 pack8(const float4 a, const float4 b) {
    int4 r;
    r.x = (int)((unsigned)f2bf(a.x) | ((unsigned)f2bf(a.y) << 16));
    r.y = (int)((unsigned)f2bf(a.z) | ((unsigned)f2bf(a.w) << 16));
    r.z = (int)((unsigned)f2bf(b.x) | ((unsigned)f2bf(b.y) << 16));
    r.w = (int)((unsigned)f2bf(b.z) | ((unsigned)f2bf(b.w) << 16));
    return r;
}

// ---------------------------------------------------------------------------
// Kernel 1: QKV projection.  C[m,f] = sum_k X[m,k] * Wqkv[f,k]
// M=4096 (B*N), K=1024, N=3072.  128x128 tile, 4 waves (2x2), K-step 64.
// Epilogue scatters to q[B,H,N,D] (scaled by 0.125*log2e), k[B,H,N,D],
// v[B,H,D,N] (transposed), all bf16.
// ---------------------------------------------------------------------------
__global__ __launch_bounds__(256) void qkv_gemm_kernel(
    const float* __restrict__ X, const float* __restrict__ W,
    u16* __restrict__ qws, u16* __restrict__ kws, u16* __restrict__ vws)
{
    __shared__ __align__(16) u16 Ash[128 * 64];
    __shared__ __align__(16) u16 Bsh[128 * 64];
    const int bm = blockIdx.x, bn = blockIdx.y;
    const int tid = threadIdx.x;
    const int lane = tid & 63, wid = tid >> 6;
    const int wm = wid >> 1, wn = wid & 1;
    const int g = lane >> 4, lq = lane & 15;

    f32x4 acc[4][4];
#pragma unroll
    for (int i = 0; i < 4; i++)
#pragma unroll
        for (int j = 0; j < 4; j++) acc[i][j] = (f32x4){0.f, 0.f, 0.f, 0.f};

    const int c = tid & 7;       // k-chunk (8 elems = 16B)
    const int r0 = tid >> 3;     // base row

    for (int kt = 0; kt < 16; ++kt) {
#pragma unroll
        for (int j = 0; j < 4; j++) {
            int row = r0 + j * 32;
            const float* pA = X + (size_t)(bm * 128 + row) * 1024 + kt * 64 + c * 8;
            float4 a0 = ((const float4*)pA)[0];
            float4 a1 = ((const float4*)pA)[1];
            *(int4*)&Ash[row * 64 + ((c ^ (row & 7)) << 3)] = pack8(a0, a1);
            const float* pB = W + (size_t)(bn * 128 + row) * 1024 + kt * 64 + c * 8;
            float4 b0 = ((const float4*)pB)[0];
            float4 b1 = ((const float4*)pB)[1];
            *(int4*)&Bsh[row * 64 + ((c ^ (row & 7)) << 3)] = pack8(b0, b1);
        }
        __syncthreads();
#pragma unroll
        for (int ka = 0; ka < 2; ka++) {
            bf16x8 af[4], bfr[4];
#pragma unroll
            for (int mt = 0; mt < 4; mt++) {
                int row = wm * 64 + mt * 16 + lq;
                af[mt] = *(const bf16x8*)&Ash[row * 64 + (((ka * 4 + g) ^ (row & 7)) << 3)];
            }
#pragma unroll
            for (int nt = 0; nt < 4; nt++) {
                int row = wn * 64 + nt * 16 + lq;
                bfr[nt] = *(const bf16x8*)&Bsh[row * 64 + (((ka * 4 + g) ^ (row & 7)) << 3)];
            }
#pragma unroll
            for (int mt = 0; mt < 4; mt++)
#pragma unroll
                for (int nt = 0; nt < 4; nt++)
                    acc[mt][nt] = MFMA16(af[mt], bfr[nt], acc[mt][nt]);
        }
        __syncthreads();
    }

    // scatter epilogue: f -> (t, h, d); m -> (b, n)
#pragma unroll
    for (int mt = 0; mt < 4; mt++) {
#pragma unroll
        for (int nt = 0; nt < 4; nt++) {
            int f = bn * 128 + wn * 64 + nt * 16 + lq;
            int t = f >> 10, h = (f >> 6) & 15, d = f & 63;
            int mbase = bm * 128 + wm * 64 + mt * 16 + g * 4;
#pragma unroll
            for (int r = 0; r < 4; r++) {
                int mm = mbase + r;
                int b = mm >> 11, n = mm & 2047;
                float v = acc[mt][nt][r];
                if (t == 0)
                    qws[((size_t)(b * 16 + h) * 2048 + n) * 64 + d] = f2bf(v * 0.18033688f); // 0.125*log2(e)
                else if (t == 1)
                    kws[((size_t)(b * 16 + h) * 2048 + n) * 64 + d] = f2bf(v);
                else
                    vws[((size_t)(b * 16 + h) * 64 + d) * 2048 + n] = f2bf(v);
            }
        }
    }
}

// ---------------------------------------------------------------------------
// Kernel 2: flash attention (no-max online softmax; logits bounded ~|10|).
// Grid (B*H=32, N/64=32). 4 waves; each wave owns 16 q-rows.
// KVBLK=64 staged in swizzled LDS. P transposed via per-wave LDS buffer.
// ---------------------------------------------------------------------------
__global__ __launch_bounds__(256) void attn_kernel(
    const u16* __restrict__ qws, const u16* __restrict__ kws,
    const u16* __restrict__ vws, u16* __restrict__ ows)
{
    __shared__ __align__(16) u16 Ksh[64 * 64];        // [kv][d], chunk-swizzled
    __shared__ __align__(16) u16 Vsh[64 * 64];        // [d][kv], chunk-swizzled
    __shared__ __align__(16) u16 Psh[4][16 * 64];     // per-wave [q][kv]
    const int bh = blockIdx.x, qt = blockIdx.y;
    const int b = bh >> 4, h = bh & 15;
    const int tid = threadIdx.x, wid = tid >> 6, lane = tid & 63;
    const int g = lane >> 4, lq = lane & 15;

    const u16* Qp = qws + ((size_t)bh * 2048 + qt * 64 + wid * 16) * 64;
    const u16* Kp = kws + (size_t)bh * 2048 * 64;
    const u16* Vp = vws + (size_t)bh * 64 * 2048;

    // Q fragments (A operand): row=lq, d-chunks g*8 and 32+g*8
    bf16x8 qf0 = *(const bf16x8*)(Qp + lq * 64 + g * 8);
    bf16x8 qf1 = *(const bf16x8*)(Qp + lq * 64 + 32 + g * 8);

    f32x4 oacc[4];
#pragma unroll
    for (int i = 0; i < 4; i++) oacc[i] = (f32x4){0.f, 0.f, 0.f, 0.f};
    f32x4 lsum = (f32x4){0.f, 0.f, 0.f, 0.f};

    const int c = tid & 7, r0 = tid >> 3;
    for (int kt = 0; kt < 32; ++kt) {
        __syncthreads();  // previous iter's LDS readers done
#pragma unroll
        for (int j = 0; j < 2; j++) {
            int row = r0 + j * 32;
            int4 kd = *(const int4*)(Kp + (size_t)(kt * 64 + row) * 64 + c * 8);
            *(int4*)&Ksh[row * 64 + ((c ^ (row & 7)) << 3)] = kd;
            int4 vd = *(const int4*)(Vp + (size_t)row * 2048 + kt * 64 + c * 8);
            *(int4*)&Vsh[row * 64 + ((c ^ (row & 7)) << 3)] = vd;
        }
        __syncthreads();

        // S = Q*K^T  (s already in log2 domain: q pre-scaled by 0.125*log2e)
        f32x4 s[4];
#pragma unroll
        for (int nt = 0; nt < 4; nt++) {
            int row = nt * 16 + lq;
            bf16x8 kb0 = *(const bf16x8*)&Ksh[row * 64 + ((g ^ (row & 7)) << 3)];
            bf16x8 kb1 = *(const bf16x8*)&Ksh[row * 64 + (((4 + g) ^ (row & 7)) << 3)];
            f32x4 z = (f32x4){0.f, 0.f, 0.f, 0.f};
            z = MFMA16(qf0, kb0, z);
            z = MFMA16(qf1, kb1, z);
            s[nt] = z;
        }
        // p = exp2(s)
#pragma unroll
        for (int nt = 0; nt < 4; nt++)
#pragma unroll
            for (int r = 0; r < 4; r++) s[nt][r] = exp2f(s[nt][r]);

        // row sums (over the 16 lanes of the group = 16 kv cols, + 4 tiles)
        f32x4 rs = s[0] + s[1] + s[2] + s[3];
#pragma unroll
        for (int m = 1; m < 16; m <<= 1) {
#pragma unroll
            for (int r = 0; r < 4; r++) rs[r] += __shfl_xor(rs[r], m);
        }
        lsum += rs;

        // store P (bf16) to per-wave LDS, transposed layout w/ chunk swizzle
#pragma unroll
        for (int nt = 0; nt < 4; nt++)
#pragma unroll
            for (int r = 0; r < 4; r++) {
                int row = g * 4 + r, kv = nt * 16 + lq;
                Psh[wid][row * 64 + ((((kv >> 3) ^ (row & 7)) << 3) | (kv & 7))] = f2bf(s[nt][r]);
            }
        asm volatile("s_waitcnt lgkmcnt(0)" ::: "memory");
        __builtin_amdgcn_sched_barrier(0);

        // PV: O[q][d] += P[q][kv] * V[kv][d]
        bf16x8 pa0 = *(const bf16x8*)&Psh[wid][lq * 64 + ((g ^ (lq & 7)) << 3)];
        bf16x8 pa1 = *(const bf16x8*)&Psh[wid][lq * 64 + (((4 + g) ^ (lq & 7)) << 3)];
#pragma unroll
        for (int dt = 0; dt < 4; dt++) {
            int vrow = dt * 16 + lq;
            bf16x8 vb0 = *(const bf16x8*)&Vsh[vrow * 64 + ((g ^ (vrow & 7)) << 3)];
            bf16x8 vb1 = *(const bf16x8*)&Vsh[vrow * 64 + (((4 + g) ^ (vrow & 7)) << 3)];
            oacc[dt] = MFMA16(pa0, vb0, oacc[dt]);
            oacc[dt] = MFMA16(pa1, vb1, oacc[dt]);
        }
    }

    // normalize + write O as [B, N, H*D] bf16
#pragma unroll
    for (int dt = 0; dt < 4; dt++)
#pragma unroll
        for (int r = 0; r < 4; r++) {
            int n = qt * 64 + wid * 16 + g * 4 + r;
            ows[((size_t)b * 2048 + n) * 1024 + h * 64 + dt * 16 + lq] =
                f2bf(oacc[dt][r] / lsum[r]);
        }
}

// ---------------------------------------------------------------------------
// Kernel 3: output projection. Out[m,o] = sum_k O[m,k]*Wout[o,k] + bias[o]
// M=4096, N=1024, K=1024. Same 128x128 structure; A is already bf16.
// ---------------------------------------------------------------------------
__global__ __launch_bounds__(256) void out_gemm_kernel(
    const u16* __restrict__ A, const float* __restrict__ W,
    const float* __restrict__ bias, float* __restrict__ Out)
{
    __shared__ __align__(16) u16 Ash[128 * 64];
    __shared__ __align__(16) u16 Bsh[128 * 64];
    const int bm = blockIdx.x, bn = blockIdx.y;
    const int tid = threadIdx.x;
    const int lane = tid & 63, wid = tid >> 6;
    const int wm = wid >> 1, wn = wid & 1;
    const int g = lane >> 4, lq = lane & 15;

    f32x4 acc[4][4];
#pragma unroll
    for (int i = 0; i < 4; i++)
#pragma unroll
        for (int j = 0; j < 4; j++) acc[i][j] = (f32x4){0.f, 0.f, 0.f, 0.f};

    const int c = tid & 7;
    const int r0 = tid >> 3;

    for (int kt = 0; kt < 16; ++kt) {
#pragma unroll
        for (int j = 0; j < 4; j++) {
            int row = r0 + j * 32;
            int4 ad = *(const int4*)(A + (size_t)(bm * 128 + row) * 1024 + kt * 64 + c * 8);
            *(int4*)&Ash[row * 64 + ((c ^ (row & 7)) << 3)] = ad;
            const float* pB = W + (size_t)(bn * 128 + row) * 1024 + kt * 64 + c * 8;
            float4 b0 = ((const float4*)pB)[0];
            float4 b1 = ((const float4*)pB)[1];
            *(int4*)&Bsh[row * 64 + ((c ^ (row & 7)) << 3)] = pack8(b0, b1);
        }
        __syncthreads();
#pragma unroll
        for (int ka = 0; ka < 2; ka++) {
            bf16x8 af[4], bfr[4];
#pragma unroll
            for (int mt = 0; mt < 4; mt++) {
                int row = wm * 64 + mt * 16 + lq;
                af[mt] = *(const bf16x8*)&Ash[row * 64 + (((ka * 4 + g) ^ (row & 7)) << 3)];
            }
#pragma unroll
            for (int nt = 0; nt < 4; nt++) {
                int row = wn * 64 + nt * 16 + lq;
                bfr[nt] = *(const bf16x8*)&Bsh[row * 64 + (((ka * 4 + g) ^ (row & 7)) << 3)];
            }
#pragma unroll
            for (int mt = 0; mt < 4; mt++)
#pragma unroll
                for (int nt = 0; nt < 4; nt++)
                    acc[mt][nt] = MFMA16(af[mt], bfr[nt], acc[mt][nt]);
        }
        __syncthreads();
    }

#pragma unroll
    for (int mt = 0; mt < 4; mt++) {
#pragma unroll
        for (int nt = 0; nt < 4; nt++) {
            int ncol = bn * 128 + wn * 64 + nt * 16 + lq;
            float bv = bias[ncol];
            int mbase = bm * 128 + wm * 64 + mt * 16 + g * 4;
#pragma unroll
            for (int r = 0; r < 4; r++)
                Out[(size_t)(mbase + r) * 1024 + ncol] = acc[mt][nt][r] + bv;
        }
    }
}

extern "C" void kernel_launch(void* const* d_in, const int* in_sizes, int n_in,
                              void* d_out, int out_size, void* d_ws, size_t ws_size,
                              hipStream_t stream) {
    const float* x     = (const float*)d_in[0];  // [2,2048,1024]
    const float* w_qkv = (const float*)d_in[1];  // [3072,1024]
    const float* w_out = (const float*)d_in[2];  // [1024,1024]
    const float* b_out = (const float*)d_in[3];  // [1024]
    float* out = (float*)d_out;                  // [2,2048,1024]

    const size_t HSZ = (size_t)2 * 16 * 2048 * 64;  // 4M elems per tensor
    u16* qws = (u16*)d_ws;
    u16* kws = qws + HSZ;
    u16* vws = kws + HSZ;
    u16* ows = vws + HSZ;

    qkv_gemm_kernel<<<dim3(32, 24), 256, 0, stream>>>(x, w_qkv, qws, kws, vws);
    attn_kernel<<<dim3(32, 32), 256, 0, stream>>>(qws, kws, vws, ows);
    out_gemm_kernel<<<dim3(32, 8), 256, 0, stream>>>(ows, w_out, b_out, out);
}

// Round 2
// 162.028 us; speedup vs baseline: 1.1834x; 1.1834x over previous
//
#include <hip/hip_runtime.h>

typedef unsigned short u16;
typedef __attribute__((ext_vector_type(4))) float f32x4;
typedef __attribute__((ext_vector_type(8))) short bf16x8;

#define MFMA16(a, b, c) __builtin_amdgcn_mfma_f32_16x16x32_bf16(a, b, c, 0, 0, 0)

// fp32 -> bf16 round-to-nearest-even (finite inputs only)
__device__ __forceinline__ u16 f2bf(float f) {
    union { float f; unsigned u; } v;
    v.f = f;
    unsigned r = v.u + 0x7FFFu + ((v.u >> 16) & 1u);
    return (u16)(r >> 16);
}

__device__ __forceinline__ int4 pack8(const float4 a, const float4 b) {
    int4 r;
    r.x = (int)((unsigned)f2bf(a.x) | ((unsigned)f2bf(a.y) << 16));
    r.y = (int)((unsigned)f2bf(a.z) | ((unsigned)f2bf(a.w) << 16));
    r.z = (int)((unsigned)f2bf(b.x) | ((unsigned)f2bf(b.y) << 16));
    r.w = (int)((unsigned)f2bf(b.z) | ((unsigned)f2bf(b.w) << 16));
    return r;
}

// async global->LDS, 16B per lane, LDS dest = wave-uniform base + lane*16
__device__ __forceinline__ void gload_lds16(const u16* g, u16* l) {
    __builtin_amdgcn_global_load_lds(
        (const __attribute__((address_space(1))) void*)g,
        (__attribute__((address_space(3))) void*)l, 16, 0, 0);
}

// ---------------------------------------------------------------------------
// Kernel 0: fp32 -> bf16 convert of x (4M), w_qkv (3M), w_out (1M) into ws.
// 8 elems/thread, 1M threads.
// ---------------------------------------------------------------------------
__global__ __launch_bounds__(256) void cvt_kernel(
    const float* __restrict__ x, const float* __restrict__ wq,
    const float* __restrict__ wo, u16* __restrict__ outb)
{
    size_t i = ((size_t)blockIdx.x * 256 + threadIdx.x) * 8;
    const float* src;
    size_t off;
    if (i < 4194304)      { src = x;  off = i; }
    else if (i < 7340032) { src = wq; off = i - 4194304; }
    else                  { src = wo; off = i - 7340032; }
    float4 a = *(const float4*)(src + off);
    float4 b = *(const float4*)(src + off + 4);
    *(int4*)(outb + i) = pack8(a, b);
}

// ---------------------------------------------------------------------------
// Kernel 1: QKV projection (bf16 GEMM). C[m,f] = sum_k X[m,k]*Wqkv[f,k]
// M=4096, K=1024, N=3072. 128x128 tile, 4 waves (2x2), K-step 64.
// global_load_lds staging: linear LDS dest, source chunk pre-XOR-swizzled
// so LDS[row][c] = global chunk (c ^ (row&7)); read with the same XOR.
// Epilogue scatters q (scaled by 0.125*log2e), k, v (transposed [B,H,D,N]).
// ---------------------------------------------------------------------------
__global__ __launch_bounds__(256) void qkv_gemm_kernel(
    const u16* __restrict__ X, const u16* __restrict__ W,
    u16* __restrict__ qws, u16* __restrict__ kws, u16* __restrict__ vws)
{
    __shared__ __align__(16) u16 Ash[128 * 64];
    __shared__ __align__(16) u16 Bsh[128 * 64];
    const int bm = blockIdx.x, bn = blockIdx.y;
    const int tid = threadIdx.x;
    const int lane = tid & 63, wid = tid >> 6;
    const int wm = wid >> 1, wn = wid & 1;
    const int g = lane >> 4, lq = lane & 15;

    f32x4 acc[4][4];
#pragma unroll
    for (int i = 0; i < 4; i++)
#pragma unroll
        for (int j = 0; j < 4; j++) acc[i][j] = (f32x4){0.f, 0.f, 0.f, 0.f};

    const int lrow = lane >> 3;            // 0..7 (row within 8-row sub-block)
    const int lchunk = (lane & 7) ^ lrow;  // pre-swizzled source 16B-chunk
    const u16* Ab = X + (size_t)(bm * 128 + lrow) * 1024 + lchunk * 8;
    const u16* Bb = W + (size_t)(bn * 128 + lrow) * 1024 + lchunk * 8;

    for (int kt = 0; kt < 16; ++kt) {
#pragma unroll
        for (int i = 0; i < 4; i++) {
            int sub = i * 4 + wid;  // wave-uniform 8-row sub-block, 0..15
            gload_lds16(Ab + (size_t)sub * 8192 + kt * 64, &Ash[sub * 512]);
            gload_lds16(Bb + (size_t)sub * 8192 + kt * 64, &Bsh[sub * 512]);
        }
        __syncthreads();
#pragma unroll
        for (int ka = 0; ka < 2; ka++) {
            bf16x8 af[4], bfr[4];
#pragma unroll
            for (int mt = 0; mt < 4; mt++) {
                int row = wm * 64 + mt * 16 + lq;
                af[mt] = *(const bf16x8*)&Ash[row * 64 + (((ka * 4 + g) ^ (row & 7)) << 3)];
            }
#pragma unroll
            for (int nt = 0; nt < 4; nt++) {
                int row = wn * 64 + nt * 16 + lq;
                bfr[nt] = *(const bf16x8*)&Bsh[row * 64 + (((ka * 4 + g) ^ (row & 7)) << 3)];
            }
#pragma unroll
            for (int mt = 0; mt < 4; mt++)
#pragma unroll
                for (int nt = 0; nt < 4; nt++)
                    acc[mt][nt] = MFMA16(af[mt], bfr[nt], acc[mt][nt]);
        }
        __syncthreads();
    }

    // scatter epilogue: f -> (t, h, d); m -> (b, n)
#pragma unroll
    for (int mt = 0; mt < 4; mt++) {
#pragma unroll
        for (int nt = 0; nt < 4; nt++) {
            int f = bn * 128 + wn * 64 + nt * 16 + lq;
            int t = f >> 10, h = (f >> 6) & 15, d = f & 63;
            int mbase = bm * 128 + wm * 64 + mt * 16 + g * 4;
            int b = mbase >> 11, n0 = mbase & 2047;
            if (t == 0) {
#pragma unroll
                for (int r = 0; r < 4; r++)
                    qws[((size_t)(b * 16 + h) * 2048 + n0 + r) * 64 + d] =
                        f2bf(acc[mt][nt][r] * 0.18033688f);  // 0.125*log2(e)
            } else if (t == 1) {
#pragma unroll
                for (int r = 0; r < 4; r++)
                    kws[((size_t)(b * 16 + h) * 2048 + n0 + r) * 64 + d] =
                        f2bf(acc[mt][nt][r]);
            } else {
                ushort4 pk;
                pk.x = f2bf(acc[mt][nt][0]);
                pk.y = f2bf(acc[mt][nt][1]);
                pk.z = f2bf(acc[mt][nt][2]);
                pk.w = f2bf(acc[mt][nt][3]);
                *(ushort4*)&vws[((size_t)(b * 16 + h) * 64 + d) * 2048 + n0] = pk;
            }
        }
    }
}

// ---------------------------------------------------------------------------
// Kernel 2: flash attention (no-max online softmax; logits bounded ~|10|).
// Grid (B*H=32, N/64=32). 4 waves; each wave owns 16 q-rows.
// KVBLK=64 staged in swizzled LDS. P transposed via per-wave LDS buffer.
// ---------------------------------------------------------------------------
__global__ __launch_bounds__(256) void attn_kernel(
    const u16* __restrict__ qws, const u16* __restrict__ kws,
    const u16* __restrict__ vws, u16* __restrict__ ows)
{
    __shared__ __align__(16) u16 Ksh[64 * 64];        // [kv][d], chunk-swizzled
    __shared__ __align__(16) u16 Vsh[64 * 64];        // [d][kv], chunk-swizzled
    __shared__ __align__(16) u16 Psh[4][16 * 64];     // per-wave [q][kv]
    const int bh = blockIdx.x, qt = blockIdx.y;
    const int b = bh >> 4, h = bh & 15;
    const int tid = threadIdx.x, wid = tid >> 6, lane = tid & 63;
    const int g = lane >> 4, lq = lane & 15;

    const u16* Qp = qws + ((size_t)bh * 2048 + qt * 64 + wid * 16) * 64;
    const u16* Kp = kws + (size_t)bh * 2048 * 64;
    const u16* Vp = vws + (size_t)bh * 64 * 2048;

    bf16x8 qf0 = *(const bf16x8*)(Qp + lq * 64 + g * 8);
    bf16x8 qf1 = *(const bf16x8*)(Qp + lq * 64 + 32 + g * 8);

    f32x4 oacc[4];
#pragma unroll
    for (int i = 0; i < 4; i++) oacc[i] = (f32x4){0.f, 0.f, 0.f, 0.f};
    f32x4 lsum = (f32x4){0.f, 0.f, 0.f, 0.f};

    const int c = tid & 7, r0 = tid >> 3;
    for (int kt = 0; kt < 32; ++kt) {
        __syncthreads();
#pragma unroll
        for (int j = 0; j < 2; j++) {
            int row = r0 + j * 32;
            int4 kd = *(const int4*)(Kp + (size_t)(kt * 64 + row) * 64 + c * 8);
            *(int4*)&Ksh[row * 64 + ((c ^ (row & 7)) << 3)] = kd;
            int4 vd = *(const int4*)(Vp + (size_t)row * 2048 + kt * 64 + c * 8);
            *(int4*)&Vsh[row * 64 + ((c ^ (row & 7)) << 3)] = vd;
        }
        __syncthreads();

        // S = Q*K^T  (log2 domain: q pre-scaled by 0.125*log2e)
        f32x4 s[4];
#pragma unroll
        for (int nt = 0; nt < 4; nt++) {
            int row = nt * 16 + lq;
            bf16x8 kb0 = *(const bf16x8*)&Ksh[row * 64 + ((g ^ (row & 7)) << 3)];
            bf16x8 kb1 = *(const bf16x8*)&Ksh[row * 64 + (((4 + g) ^ (row & 7)) << 3)];
            f32x4 z = (f32x4){0.f, 0.f, 0.f, 0.f};
            z = MFMA16(qf0, kb0, z);
            z = MFMA16(qf1, kb1, z);
            s[nt] = z;
        }
#pragma unroll
        for (int nt = 0; nt < 4; nt++)
#pragma unroll
            for (int r = 0; r < 4; r++) s[nt][r] = exp2f(s[nt][r]);

        f32x4 rs = s[0] + s[1] + s[2] + s[3];
#pragma unroll
        for (int m = 1; m < 16; m <<= 1) {
#pragma unroll
            for (int r = 0; r < 4; r++) rs[r] += __shfl_xor(rs[r], m);
        }
        lsum += rs;

#pragma unroll
        for (int nt = 0; nt < 4; nt++)
#pragma unroll
            for (int r = 0; r < 4; r++) {
                int row = g * 4 + r, kv = nt * 16 + lq;
                Psh[wid][row * 64 + ((((kv >> 3) ^ (row & 7)) << 3) | (kv & 7))] = f2bf(s[nt][r]);
            }
        asm volatile("s_waitcnt lgkmcnt(0)" ::: "memory");
        __builtin_amdgcn_sched_barrier(0);

        bf16x8 pa0 = *(const bf16x8*)&Psh[wid][lq * 64 + ((g ^ (lq & 7)) << 3)];
        bf16x8 pa1 = *(const bf16x8*)&Psh[wid][lq * 64 + (((4 + g) ^ (lq & 7)) << 3)];
#pragma unroll
        for (int dt = 0; dt < 4; dt++) {
            int vrow = dt * 16 + lq;
            bf16x8 vb0 = *(const bf16x8*)&Vsh[vrow * 64 + ((g ^ (vrow & 7)) << 3)];
            bf16x8 vb1 = *(const bf16x8*)&Vsh[vrow * 64 + (((4 + g) ^ (vrow & 7)) << 3)];
            oacc[dt] = MFMA16(pa0, vb0, oacc[dt]);
            oacc[dt] = MFMA16(pa1, vb1, oacc[dt]);
        }
    }

#pragma unroll
    for (int dt = 0; dt < 4; dt++)
#pragma unroll
        for (int r = 0; r < 4; r++) {
            int n = qt * 64 + wid * 16 + g * 4 + r;
            ows[((size_t)b * 2048 + n) * 1024 + h * 64 + dt * 16 + lq] =
                f2bf(oacc[dt][r] / lsum[r]);
        }
}

// ---------------------------------------------------------------------------
// Kernel 3: output projection. Out[m,o] = sum_k O[m,k]*Wout[o,k] + bias[o]
// M=4096, N=1024, K=1024. bf16 GEMM, global_load_lds staging, fp32 out.
// ---------------------------------------------------------------------------
__global__ __launch_bounds__(256) void out_gemm_kernel(
    const u16* __restrict__ A, const u16* __restrict__ W,
    const float* __restrict__ bias, float* __restrict__ Out)
{
    __shared__ __align__(16) u16 Ash[128 * 64];
    __shared__ __align__(16) u16 Bsh[128 * 64];
    const int bm = blockIdx.x, bn = blockIdx.y;
    const int tid = threadIdx.x;
    const int lane = tid & 63, wid = tid >> 6;
    const int wm = wid >> 1, wn = wid & 1;
    const int g = lane >> 4, lq = lane & 15;

    f32x4 acc[4][4];
#pragma unroll
    for (int i = 0; i < 4; i++)
#pragma unroll
        for (int j = 0; j < 4; j++) acc[i][j] = (f32x4){0.f, 0.f, 0.f, 0.f};

    const int lrow = lane >> 3;
    const int lchunk = (lane & 7) ^ lrow;
    const u16* Ab = A + (size_t)(bm * 128 + lrow) * 1024 + lchunk * 8;
    const u16* Bb = W + (size_t)(bn * 128 + lrow) * 1024 + lchunk * 8;

    for (int kt = 0; kt < 16; ++kt) {
#pragma unroll
        for (int i = 0; i < 4; i++) {
            int sub = i * 4 + wid;
            gload_lds16(Ab + (size_t)sub * 8192 + kt * 64, &Ash[sub * 512]);
            gload_lds16(Bb + (size_t)sub * 8192 + kt * 64, &Bsh[sub * 512]);
        }
        __syncthreads();
#pragma unroll
        for (int ka = 0; ka < 2; ka++) {
            bf16x8 af[4], bfr[4];
#pragma unroll
            for (int mt = 0; mt < 4; mt++) {
                int row = wm * 64 + mt * 16 + lq;
                af[mt] = *(const bf16x8*)&Ash[row * 64 + (((ka * 4 + g) ^ (row & 7)) << 3)];
            }
#pragma unroll
            for (int nt = 0; nt < 4; nt++) {
                int row = wn * 64 + nt * 16 + lq;
                bfr[nt] = *(const bf16x8*)&Bsh[row * 64 + (((ka * 4 + g) ^ (row & 7)) << 3)];
            }
#pragma unroll
            for (int mt = 0; mt < 4; mt++)
#pragma unroll
                for (int nt = 0; nt < 4; nt++)
                    acc[mt][nt] = MFMA16(af[mt], bfr[nt], acc[mt][nt]);
        }
        __syncthreads();
    }

#pragma unroll
    for (int mt = 0; mt < 4; mt++) {
#pragma unroll
        for (int nt = 0; nt < 4; nt++) {
            int ncol = bn * 128 + wn * 64 + nt * 16 + lq;
            float bv = bias[ncol];
            int mbase = bm * 128 + wm * 64 + mt * 16 + g * 4;
#pragma unroll
            for (int r = 0; r < 4; r++)
                Out[(size_t)(mbase + r) * 1024 + ncol] = acc[mt][nt][r] + bv;
        }
    }
}

extern "C" void kernel_launch(void* const* d_in, const int* in_sizes, int n_in,
                              void* d_out, int out_size, void* d_ws, size_t ws_size,
                              hipStream_t stream) {
    const float* x     = (const float*)d_in[0];  // [2,2048,1024]
    const float* w_qkv = (const float*)d_in[1];  // [3072,1024]
    const float* w_out = (const float*)d_in[2];  // [1024,1024]
    const float* b_out = (const float*)d_in[3];  // [1024]
    float* out = (float*)d_out;                  // [2,2048,1024]

    u16* xb  = (u16*)d_ws;                       // 4M elems
    u16* wqb = xb + 4194304;                     // 3M
    u16* wob = wqb + 3145728;                    // 1M
    u16* qws = wob + 1048576;                    // 4M
    u16* kws = qws + 4194304;                    // 4M
    u16* vws = kws + 4194304;                    // 4M
    u16* ows = vws + 4194304;                    // 4M

    cvt_kernel<<<4096, 256, 0, stream>>>(x, w_qkv, w_out, xb);
    qkv_gemm_kernel<<<dim3(32, 24), 256, 0, stream>>>(xb, wqb, qws, kws, vws);
    attn_kernel<<<dim3(32, 32), 256, 0, stream>>>(qws, kws, vws, ows);
    out_gemm_kernel<<<dim3(32, 8), 256, 0, stream>>>(ows, wob, b_out, out);
}